// Round 3
// baseline (490.483 us; speedup 1.0000x reference)
//
#include <hip/hip_runtime.h>

typedef __attribute__((ext_vector_type(8))) __bf16 bf16x8;
typedef __attribute__((ext_vector_type(4))) float f32x4;
typedef __attribute__((ext_vector_type(4))) short short4v;

#define LOG2E 1.4426950408889634f

// ---- workspace byte offsets ----
// PART/invD alias the Xt region (Xt is dead after k_conv3; stream-serial).
#define XT_OFF   0ul          // Xt  : bf16 [8][4096][256]
#define PART_OFF 0ul          // PART: f32  [8][64][2048] column-sum partials (aliases Xt)
#define ID_OFF   4194304ul    // invD: f32  [8][2048]
#define TT_OFF   16777216ul   // Tt  : bf16 [8][2048][256]  (x_theta, n-major)
#define PT_OFF   25165824ul   // Pt  : bf16 [8][2048][256]  (x_phi, n-major)
#define G_OFF    33554432ul   // G   : bf16 [8][256][2048]  (x_g, c-major; scaled in-place by invD)
#define OT_OFF   41943040ul   // OT  : bf16 [8][4096][128]  (out_nl transposed, p-major)
#define W3_OFF   50331648ul   // W3  : bf16 [384][256]
#define WM_OFF   50528256ul   // Wm  : bf16 [256][128]
#define WS_NEED  50593792ul

// ---------------- weights cast ----------------
__global__ __launch_bounds__(256) void k_weights(const float* wt, const float* wp,
                                                 const float* wg, const float* wm,
                                                 __bf16* W3, __bf16* Wm){
  int idx = blockIdx.x*256 + threadIdx.x;
  if (idx < 98304){
    float v = (idx < 32768) ? wt[idx] : (idx < 65536) ? wp[idx - 32768] : wg[idx - 65536];
    W3[idx] = (__bf16)v;
  } else if (idx < 131072){
    Wm[idx - 98304] = (__bf16)wm[idx - 98304];
  }
}

// ---------------- transpose+cast x: (b,256,4096) f32 -> Xt (b,4096,256) bf16 ----------------
__global__ __launch_bounds__(256) void k_xt(const float* x, __bf16* Xt){
  __shared__ float tile[64][65];
  int b = blockIdx.z, c0 = blockIdx.y*64, p0 = blockIdx.x*64;
  int t = threadIdx.x, col = t & 63, r0 = t >> 6;
  const float* xb = x + ((size_t)b*256 + c0)*4096 + p0;
  #pragma unroll
  for (int rr = 0; rr < 16; ++rr){
    int row = rr*4 + r0;
    tile[row][col] = xb[(size_t)row*4096 + col];
  }
  __syncthreads();
  __bf16* xo = Xt + ((size_t)b*4096 + p0)*256 + c0;
  #pragma unroll
  for (int rr = 0; rr < 16; ++rr){
    int prow = rr*4 + r0;
    xo[(size_t)prow*256 + col] = (__bf16)tile[col][prow];
  }
}

// ---------------- conv3: Xt(4096x256) * W3^T(384x256) -> theta/phi/g in attn layouts ----------------
__global__ __launch_bounds__(256) void k_conv3(const __bf16* Xt, const __bf16* W3,
                                               __bf16* Tt, __bf16* Pt, __bf16* G){
  __shared__ __bf16 As[128*72];
  __shared__ __bf16 Bs[64*72];
  int b = blockIdx.z, p0 = blockIdx.x*128, o0 = blockIdx.y*64;
  int tid = threadIdx.x, lane = tid & 63, wave = tid >> 6;
  int wm = wave >> 1, wn = wave & 1;
  f32x4 acc[4][2] = {};
  const __bf16* Ab = Xt + ((size_t)b*4096 + p0)*256;
  const __bf16* Bb = W3 + (size_t)o0*256;
  for (int kc = 0; kc < 4; ++kc){
    int k0 = kc*64;
    #pragma unroll
    for (int it = 0; it < 4; ++it){
      int s = tid + it*256, row = s >> 3, sk = s & 7;
      *(uint4*)&As[row*72 + sk*8] = *(const uint4*)(Ab + (size_t)row*256 + k0 + sk*8);
    }
    #pragma unroll
    for (int it = 0; it < 2; ++it){
      int s = tid + it*256, row = s >> 3, sk = s & 7;
      *(uint4*)&Bs[row*72 + sk*8] = *(const uint4*)(Bb + (size_t)row*256 + k0 + sk*8);
    }
    __syncthreads();
    #pragma unroll
    for (int ks = 0; ks < 2; ++ks){
      int koff = ks*32 + (lane>>4)*8;
      bf16x8 af[4], bfr[2];
      #pragma unroll
      for (int fm = 0; fm < 4; ++fm)
        af[fm] = *(const bf16x8*)&As[(wm*64 + fm*16 + (lane&15))*72 + koff];
      #pragma unroll
      for (int fn = 0; fn < 2; ++fn)
        bfr[fn] = *(const bf16x8*)&Bs[(wn*32 + fn*16 + (lane&15))*72 + koff];
      #pragma unroll
      for (int fm = 0; fm < 4; ++fm)
        #pragma unroll
        for (int fn = 0; fn < 2; ++fn)
          acc[fm][fn] = __builtin_amdgcn_mfma_f32_16x16x32_bf16(af[fm], bfr[fn], acc[fm][fn], 0, 0, 0);
    }
    __syncthreads();
  }
  // scatter per the reshape-view: flat = o*4096+p -> c = 2o+(p>>11), n = p&2047
  #pragma unroll
  for (int fm = 0; fm < 4; ++fm)
    #pragma unroll
    for (int fn = 0; fn < 2; ++fn)
      #pragma unroll
      for (int r = 0; r < 4; ++r){
        int p = p0 + wm*64 + fm*16 + (lane>>4)*4 + r;
        int o = o0 + wn*32 + fn*16 + (lane&15);
        __bf16 v = (__bf16)acc[fm][fn][r];
        int i = p & 2047, ph = p >> 11;
        if (o < 128)      Tt[((size_t)b*2048 + i)*256 + 2*o + ph] = v;
        else if (o < 256) Pt[((size_t)b*2048 + i)*256 + 2*(o-128) + ph] = v;
        else              G [((size_t)b*256 + 2*(o-256) + ph)*2048 + i] = v;
      }
}

// ---------------- pass A: column sums of exp(s) -> PART ----------------
// i-tile 32, j-half split per block: grid 1024 -> 3-4 blocks/CU. No barriers.
__global__ __launch_bounds__(256, 3) void k_colsum(const __bf16* Tt, const __bf16* Pt, float* PART){
  int bid = blockIdx.x;
  int b = bid & 7;                      // batch -> XCD (wgid%8)
  int r2 = bid >> 3;
  int it = r2 & 63, jh = r2 >> 6;
  int i0 = it*32;
  int tid = threadIdx.x, lane = tid & 63, w = tid >> 6;
  int lr = lane & 15, kq = lane >> 4;
  int jl = w*16 + lr;
  const __bf16* Tb = Tt + ((size_t)b*2048 + i0)*256;
  const __bf16* Pb = Pt + (size_t)b*2048*256;
  bf16x8 q[2][8];
  #pragma unroll
  for (int fm = 0; fm < 2; ++fm)
    #pragma unroll
    for (int ks = 0; ks < 8; ++ks)
      q[fm][ks] = *(const bf16x8*)(Tb + (size_t)(fm*16 + lr)*256 + ks*32 + kq*8);
  for (int ch = 0; ch < 16; ++ch){
    int j0 = jh*1024 + ch*64;
    const __bf16* pr = Pb + (size_t)(j0 + jl)*256 + kq*8;
    bf16x8 bq[8];
    #pragma unroll
    for (int ks = 0; ks < 8; ++ks) bq[ks] = *(const bf16x8*)(pr + ks*32);
    f32x4 saA[2] = {}, saB[2] = {};
    #pragma unroll
    for (int ks = 0; ks < 4; ++ks){
      saA[0] = __builtin_amdgcn_mfma_f32_16x16x32_bf16(q[0][ks], bq[ks], saA[0], 0, 0, 0);
      saA[1] = __builtin_amdgcn_mfma_f32_16x16x32_bf16(q[1][ks], bq[ks], saA[1], 0, 0, 0);
      saB[0] = __builtin_amdgcn_mfma_f32_16x16x32_bf16(q[0][ks+4], bq[ks+4], saB[0], 0, 0, 0);
      saB[1] = __builtin_amdgcn_mfma_f32_16x16x32_bf16(q[1][ks+4], bq[ks+4], saB[1], 0, 0, 0);
    }
    float v = 0.f;
    #pragma unroll
    for (int fm = 0; fm < 2; ++fm){
      f32x4 sa = saA[fm] + saB[fm];
      #pragma unroll
      for (int r = 0; r < 4; ++r)
        v += exp2f(sa[r] * LOG2E);
    }
    v += __shfl_xor(v, 16);
    v += __shfl_xor(v, 32);
    if (kq == 0) PART[((size_t)b*64 + it)*2048 + j0 + jl] = v;
  }
}

// ---------------- reduce partials -> invD = 1/D ----------------
__global__ __launch_bounds__(256) void k_invd(const float* PART, float* invD){
  int idx = blockIdx.x*256 + threadIdx.x;   // 16384
  int b = idx >> 11, j = idx & 2047;
  float s = 0.f;
  #pragma unroll
  for (int it = 0; it < 64; ++it) s += PART[((size_t)b*64 + it)*2048 + j];
  invD[idx] = 1.0f / s;
}

// ---------------- scale G in place: G[b][c][j] *= invD[b][j] ----------------
__global__ __launch_bounds__(256) void k_gscale(__bf16* G, const float* invD){
  int bid = blockIdx.x;                 // 2048 = 8 b * 256 c
  int b = bid >> 8, c = bid & 255;
  int j0 = threadIdx.x * 8;
  __bf16* gp = G + ((size_t)b*256 + c)*2048 + j0;
  bf16x8 g = *(const bf16x8*)gp;
  const float* dp = invD + (size_t)b*2048 + j0;
  f32x4 d0 = *(const f32x4*)dp;
  f32x4 d1 = *(const f32x4*)(dp + 4);
  bf16x8 o;
  #pragma unroll
  for (int e = 0; e < 4; ++e){
    o[e]   = (__bf16)((float)g[e]   * d0[e]);
    o[e+4] = (__bf16)((float)g[e+4] * d1[e]);
  }
  *(bf16x8*)gp = o;
}

// ---------------- pass B: swapped QK -> direct PV (16x16x16), no barriers in loop ----------------
// block: 512 thr / 8 waves, i-tile 64. wave = iw(4: 16-i slice) x jw(2: 16-j slice of 32-j chunk).
// s^T = mfma(A=phi, B=theta): col=i, row=j => exp2 of rows IS the PV A-frag (k = kq*4+e).
// PV accumulates partial (per-jw) out; one LDS reduce + epilogue at the end.
__global__ __launch_bounds__(512, 2) void k_attn(const __bf16* Tt, const __bf16* Pt,
                                                 const __bf16* G, __bf16* OT){
  __shared__ float red[4*16*64*4];      // [iw][fc][lane][4] = 64 KB
  int bid = blockIdx.x;
  int b = bid & 7, it = bid >> 3, i0 = it*64;    // batch -> XCD
  int tid = threadIdx.x, lane = tid & 63, w = tid >> 6;
  int lr = lane & 15, kq = lane >> 4;
  int iw = w >> 1, jw = w & 1;
  const __bf16* Tb = Tt + ((size_t)b*2048 + i0 + iw*16)*256;
  const __bf16* Pb = Pt + (size_t)b*2048*256;
  const __bf16* Gb = G + (size_t)b*256*2048;
  // hoist theta B-frags: 16 i-rows x 256 k (8 x bf16x8 = 32 VGPR)
  bf16x8 q[8];
  #pragma unroll
  for (int ks = 0; ks < 8; ++ks)
    q[ks] = *(const bf16x8*)(Tb + (size_t)lr*256 + ks*32 + kq*8);
  f32x4 acc[16] = {};
  for (int ch = 0; ch < 64; ++ch){
    int j0 = ch*32;
    // QK^T swapped: A = phi rows (this wave's 16 j), B = theta (16 i)
    const __bf16* pr = Pb + (size_t)(j0 + jw*16 + lr)*256 + kq*8;
    bf16x8 bq[8];
    #pragma unroll
    for (int ks = 0; ks < 8; ++ks) bq[ks] = *(const bf16x8*)(pr + ks*32);
    f32x4 saA = {}, saB = {};
    #pragma unroll
    for (int ks = 0; ks < 4; ++ks){
      saA = __builtin_amdgcn_mfma_f32_16x16x32_bf16(bq[ks],   q[ks],   saA, 0, 0, 0);
      saB = __builtin_amdgcn_mfma_f32_16x16x32_bf16(bq[ks+4], q[ks+4], saB, 0, 0, 0);
    }
    f32x4 sa = saA + saB;
    // P = exp2(s*log2e) in bf16; lane layout (col=i, row=j=kq*4+r) == PV A-frag
    short4v pa;
    #pragma unroll
    for (int r = 0; r < 4; ++r){
      __bf16 h = (__bf16)exp2f(sa[r] * LOG2E);
      pa[r] = __builtin_bit_cast(short, h);
    }
    // PV: acc[fc] += P(16i x 16j) * G'(16j x 16c), B-frags straight from L2
    #pragma unroll
    for (int fc = 0; fc < 16; ++fc){
      short4v gv = *(const short4v*)(const void*)(Gb + (size_t)(fc*16 + lr)*2048 + j0 + jw*16 + kq*4);
      acc[fc] = __builtin_amdgcn_mfma_f32_16x16x16bf16_1k(pa, gv, acc[fc], 0, 0, 0);
    }
  }
  // cross-jw reduce (one barrier per block)
  if (jw == 1){
    #pragma unroll
    for (int fc = 0; fc < 16; ++fc)
      *(f32x4*)&red[((iw*16 + fc)*64 + lane)*4] = acc[fc];
  }
  __syncthreads();
  if (jw == 0){
    #pragma unroll
    for (int fc = 0; fc < 16; ++fc)
      acc[fc] += *(const f32x4*)&red[((iw*16 + fc)*64 + lane)*4];
    // epilogue: out[i][c'] -> OT[p][ic], ic=c'>>1, p=(c'&1)*2048+i
    #pragma unroll
    for (int fc = 0; fc < 16; ++fc)
      #pragma unroll
      for (int r = 0; r < 4; ++r){
        int i = i0 + iw*16 + kq*4 + r;
        int cp = fc*16 + lr;
        int p = ((cp & 1) << 11) + i;
        OT[((size_t)b*4096 + p)*128 + (cp >> 1)] = (__bf16)acc[fc][r];
      }
  }
}

// ---------------- mask conv + residual: OT(4096x128) * Wm^T(256x128) + x ----------------
__global__ __launch_bounds__(256) void k_mask(const __bf16* OT, const __bf16* Wm,
                                              const float* x, float* out){
  __shared__ __bf16 As[128*72];
  __shared__ __bf16 Bs[64*72];
  int b = blockIdx.z, p0 = blockIdx.x*128, o0 = blockIdx.y*64;
  int tid = threadIdx.x, lane = tid & 63, wave = tid >> 6;
  int wm = wave >> 1, wn = wave & 1;
  f32x4 acc[4][2] = {};
  const __bf16* Ab = OT + ((size_t)b*4096 + p0)*128;
  const __bf16* Bb = Wm + (size_t)o0*128;
  for (int kc = 0; kc < 2; ++kc){
    int k0 = kc*64;
    #pragma unroll
    for (int itc = 0; itc < 4; ++itc){
      int s = tid + itc*256, row = s >> 3, sk = s & 7;
      *(uint4*)&As[row*72 + sk*8] = *(const uint4*)(Ab + (size_t)row*128 + k0 + sk*8);
    }
    #pragma unroll
    for (int itc = 0; itc < 2; ++itc){
      int s = tid + itc*256, row = s >> 3, sk = s & 7;
      *(uint4*)&Bs[row*72 + sk*8] = *(const uint4*)(Bb + (size_t)row*128 + k0 + sk*8);
    }
    __syncthreads();
    #pragma unroll
    for (int ks = 0; ks < 2; ++ks){
      int koff = ks*32 + (lane>>4)*8;
      bf16x8 af[4], bfr[2];
      #pragma unroll
      for (int fm = 0; fm < 4; ++fm)
        af[fm] = *(const bf16x8*)&As[(wm*64 + fm*16 + (lane&15))*72 + koff];
      #pragma unroll
      for (int fn = 0; fn < 2; ++fn)
        bfr[fn] = *(const bf16x8*)&Bs[(wn*32 + fn*16 + (lane&15))*72 + koff];
      #pragma unroll
      for (int fm = 0; fm < 4; ++fm)
        #pragma unroll
        for (int fn = 0; fn < 2; ++fn)
          acc[fm][fn] = __builtin_amdgcn_mfma_f32_16x16x32_bf16(af[fm], bfr[fn], acc[fm][fn], 0, 0, 0);
    }
    __syncthreads();
  }
  #pragma unroll
  for (int fm = 0; fm < 4; ++fm)
    #pragma unroll
    for (int fn = 0; fn < 2; ++fn){
      int pb = p0 + wm*64 + fm*16 + (lane>>4)*4;
      int o = o0 + wn*32 + fn*16 + (lane&15);
      size_t idx = ((size_t)b*256 + o)*4096 + pb;
      f32x4 xv = *(const f32x4*)(x + idx);
      f32x4 ov = acc[fm][fn] + xv;
      *(f32x4*)(out + idx) = ov;
    }
}

extern "C" void kernel_launch(void* const* d_in, const int* in_sizes, int n_in,
                              void* d_out, int out_size, void* d_ws, size_t ws_size,
                              hipStream_t stream){
  if (ws_size < WS_NEED) return;  // workspace too small; fail visibly
  const float* x  = (const float*)d_in[0];
  const float* wt = (const float*)d_in[1];
  const float* wp = (const float*)d_in[2];
  const float* wg = (const float*)d_in[3];
  const float* wm = (const float*)d_in[4];
  char* ws = (char*)d_ws;
  __bf16* Xt  = (__bf16*)(ws + XT_OFF);
  __bf16* Tt  = (__bf16*)(ws + TT_OFF);
  __bf16* Pt  = (__bf16*)(ws + PT_OFF);
  __bf16* G   = (__bf16*)(ws + G_OFF);
  __bf16* OT  = (__bf16*)(ws + OT_OFF);
  __bf16* W3  = (__bf16*)(ws + W3_OFF);
  __bf16* Wm  = (__bf16*)(ws + WM_OFF);
  float* PART = (float*)(ws + PART_OFF);   // aliases Xt (dead after k_conv3)
  float* invD = (float*)(ws + ID_OFF);
  float* out  = (float*)d_out;

  k_weights<<<512, 256, 0, stream>>>(wt, wp, wg, wm, W3, Wm);
  k_xt<<<dim3(64, 4, 8), 256, 0, stream>>>(x, Xt);
  k_conv3<<<dim3(32, 6, 8), 256, 0, stream>>>(Xt, W3, Tt, Pt, G);
  k_colsum<<<1024, 256, 0, stream>>>(Tt, Pt, PART);
  k_invd<<<64, 256, 0, stream>>>(PART, invD);
  k_gscale<<<2048, 256, 0, stream>>>(G, invD);
  k_attn<<<256, 512, 0, stream>>>(Tt, Pt, G, OT);
  k_mask<<<dim3(32, 4, 8), 256, 0, stream>>>(OT, Wm, x, out);
}

// Round 4
// 412.836 us; speedup vs baseline: 1.1881x; 1.1881x over previous
//
#include <hip/hip_runtime.h>

typedef __attribute__((ext_vector_type(8))) __bf16 bf16x8;
typedef __attribute__((ext_vector_type(4))) float f32x4;

#define LOG2E 1.4426950408889634f

// ---- workspace byte offsets ----
// PART/invD alias the Xt region (Xt is dead after k_conv3; stream-serial).
#define XT_OFF   0ul          // Xt  : bf16 [8][4096][256]
#define PART_OFF 0ul          // PART: f32  [8][64][2048] column-sum partials (aliases Xt)
#define ID_OFF   4194304ul    // invD: f32  [8][2048]
#define TT_OFF   16777216ul   // Tt  : bf16 [8][2048][256]  (x_theta, n-major)
#define PT_OFF   25165824ul   // Pt  : bf16 [8][2048][256]  (x_phi, n-major)
#define G_OFF    33554432ul   // G   : bf16 [8][256][2048]  (x_g, c-major; scaled in-place by invD)
#define OT_OFF   41943040ul   // OT  : bf16 [8][4096][128]  (out_nl transposed, p-major)
#define W3_OFF   50331648ul   // W3  : bf16 [384][256]
#define WM_OFF   50528256ul   // Wm  : bf16 [256][128]
#define WS_NEED  50593792ul

// ---------------- weights cast ----------------
__global__ __launch_bounds__(256) void k_weights(const float* wt, const float* wp,
                                                 const float* wg, const float* wm,
                                                 __bf16* W3, __bf16* Wm){
  int idx = blockIdx.x*256 + threadIdx.x;
  if (idx < 98304){
    float v = (idx < 32768) ? wt[idx] : (idx < 65536) ? wp[idx - 32768] : wg[idx - 65536];
    W3[idx] = (__bf16)v;
  } else if (idx < 131072){
    Wm[idx - 98304] = (__bf16)wm[idx - 98304];
  }
}

// ---------------- transpose+cast x: (b,256,4096) f32 -> Xt (b,4096,256) bf16 ----------------
__global__ __launch_bounds__(256) void k_xt(const float* x, __bf16* Xt){
  __shared__ float tile[64][65];
  int b = blockIdx.z, c0 = blockIdx.y*64, p0 = blockIdx.x*64;
  int t = threadIdx.x, col = t & 63, r0 = t >> 6;
  const float* xb = x + ((size_t)b*256 + c0)*4096 + p0;
  #pragma unroll
  for (int rr = 0; rr < 16; ++rr){
    int row = rr*4 + r0;
    tile[row][col] = xb[(size_t)row*4096 + col];
  }
  __syncthreads();
  __bf16* xo = Xt + ((size_t)b*4096 + p0)*256 + c0;
  #pragma unroll
  for (int rr = 0; rr < 16; ++rr){
    int prow = rr*4 + r0;
    xo[(size_t)prow*256 + col] = (__bf16)tile[col][prow];
  }
}

// ---------------- conv3: Xt(4096x256) * W3^T(384x256) -> theta/phi/g in attn layouts ----------------
__global__ __launch_bounds__(256) void k_conv3(const __bf16* Xt, const __bf16* W3,
                                               __bf16* Tt, __bf16* Pt, __bf16* G){
  __shared__ __bf16 As[128*72];
  __shared__ __bf16 Bs[64*72];
  int b = blockIdx.z, p0 = blockIdx.x*128, o0 = blockIdx.y*64;
  int tid = threadIdx.x, lane = tid & 63, wave = tid >> 6;
  int wm = wave >> 1, wn = wave & 1;
  f32x4 acc[4][2] = {};
  const __bf16* Ab = Xt + ((size_t)b*4096 + p0)*256;
  const __bf16* Bb = W3 + (size_t)o0*256;
  for (int kc = 0; kc < 4; ++kc){
    int k0 = kc*64;
    #pragma unroll
    for (int it = 0; it < 4; ++it){
      int s = tid + it*256, row = s >> 3, sk = s & 7;
      *(uint4*)&As[row*72 + sk*8] = *(const uint4*)(Ab + (size_t)row*256 + k0 + sk*8);
    }
    #pragma unroll
    for (int it = 0; it < 2; ++it){
      int s = tid + it*256, row = s >> 3, sk = s & 7;
      *(uint4*)&Bs[row*72 + sk*8] = *(const uint4*)(Bb + (size_t)row*256 + k0 + sk*8);
    }
    __syncthreads();
    #pragma unroll
    for (int ks = 0; ks < 2; ++ks){
      int koff = ks*32 + (lane>>4)*8;
      bf16x8 af[4], bfr[2];
      #pragma unroll
      for (int fm = 0; fm < 4; ++fm)
        af[fm] = *(const bf16x8*)&As[(wm*64 + fm*16 + (lane&15))*72 + koff];
      #pragma unroll
      for (int fn = 0; fn < 2; ++fn)
        bfr[fn] = *(const bf16x8*)&Bs[(wn*32 + fn*16 + (lane&15))*72 + koff];
      #pragma unroll
      for (int fm = 0; fm < 4; ++fm)
        #pragma unroll
        for (int fn = 0; fn < 2; ++fn)
          acc[fm][fn] = __builtin_amdgcn_mfma_f32_16x16x32_bf16(af[fm], bfr[fn], acc[fm][fn], 0, 0, 0);
    }
    __syncthreads();
  }
  // scatter per the reshape-view: flat = o*4096+p -> c = 2o+(p>>11), n = p&2047
  #pragma unroll
  for (int fm = 0; fm < 4; ++fm)
    #pragma unroll
    for (int fn = 0; fn < 2; ++fn)
      #pragma unroll
      for (int r = 0; r < 4; ++r){
        int p = p0 + wm*64 + fm*16 + (lane>>4)*4 + r;
        int o = o0 + wn*32 + fn*16 + (lane&15);
        __bf16 v = (__bf16)acc[fm][fn][r];
        int i = p & 2047, ph = p >> 11;
        if (o < 128)      Tt[((size_t)b*2048 + i)*256 + 2*o + ph] = v;
        else if (o < 256) Pt[((size_t)b*2048 + i)*256 + 2*(o-128) + ph] = v;
        else              G [((size_t)b*256 + 2*(o-256) + ph)*2048 + i] = v;
      }
}

// ---------------- pass A: column sums of exp(s) -> PART ----------------
// i-tile 32, 512 thr / 8 waves, j-chunk 128 staged in LDS, q in regs, 2 barriers/chunk.
__global__ __launch_bounds__(512, 2) void k_colsum(const __bf16* Tt, const __bf16* Pt, float* PART){
  __shared__ __bf16 Ps[128*260];
  int bid = blockIdx.x;
  int b = bid & 7, it = bid >> 3, i0 = it*32;   // batch -> XCD
  int tid = threadIdx.x, lane = tid & 63, w = tid >> 6;
  int lr = lane & 15, kq = lane >> 4;
  const __bf16* Tb = Tt + ((size_t)b*2048 + i0)*256;
  const __bf16* Pb = Pt + (size_t)b*2048*256;
  // hoist theta fragments: 32 i rows (same for all waves)
  bf16x8 q[2][8];
  #pragma unroll
  for (int fm = 0; fm < 2; ++fm)
    #pragma unroll
    for (int ks = 0; ks < 8; ++ks)
      q[fm][ks] = *(const bf16x8*)(Tb + (size_t)(fm*16 + lr)*256 + ks*32 + kq*8);
  // prologue: stage chunk 0
  uint4 st[8];
  #pragma unroll
  for (int u = 0; u < 8; ++u){
    int s = u*512 + tid, row = s >> 5, sk = s & 31;
    st[u] = *(const uint4*)(Pb + (size_t)row*256 + sk*8);
  }
  #pragma unroll
  for (int u = 0; u < 8; ++u){
    int s = u*512 + tid, row = s >> 5, sk = s & 31;
    *(uint4*)&Ps[row*260 + sk*8] = st[u];
  }
  __syncthreads();
  for (int ch = 0; ch < 16; ++ch){
    // issue next-chunk global loads (overlap with QK below)
    if (ch < 15){
      int j0n = (ch + 1)*128;
      #pragma unroll
      for (int u = 0; u < 8; ++u){
        int s = u*512 + tid, row = s >> 5, sk = s & 31;
        st[u] = *(const uint4*)(Pb + (size_t)(j0n + row)*256 + sk*8);
      }
    }
    // QK: A = q regs, B = phi rows from LDS
    f32x4 sa[2] = {};
    #pragma unroll
    for (int ks = 0; ks < 8; ++ks){
      bf16x8 bq = *(const bf16x8*)&Ps[(w*16 + lr)*260 + ks*32 + kq*8];
      sa[0] = __builtin_amdgcn_mfma_f32_16x16x32_bf16(q[0][ks], bq, sa[0], 0, 0, 0);
      sa[1] = __builtin_amdgcn_mfma_f32_16x16x32_bf16(q[1][ks], bq, sa[1], 0, 0, 0);
    }
    float v = 0.f;
    #pragma unroll
    for (int fm = 0; fm < 2; ++fm)
      #pragma unroll
      for (int r = 0; r < 4; ++r)
        v += exp2f(sa[fm][r] * LOG2E);
    v += __shfl_xor(v, 16);
    v += __shfl_xor(v, 32);
    if (kq == 0) PART[((size_t)b*64 + it)*2048 + ch*128 + w*16 + lr] = v;
    __syncthreads();   // all waves done reading Ps
    if (ch < 15){
      #pragma unroll
      for (int u = 0; u < 8; ++u){
        int s = u*512 + tid, row = s >> 5, sk = s & 31;
        *(uint4*)&Ps[row*260 + sk*8] = st[u];
      }
    }
    __syncthreads();   // staged chunk ready
  }
}

// ---------------- reduce partials -> invD = 1/D ----------------
__global__ __launch_bounds__(256) void k_invd(const float* PART, float* invD){
  int idx = blockIdx.x*256 + threadIdx.x;   // 16384
  int b = idx >> 11, j = idx & 2047;
  float s = 0.f;
  #pragma unroll
  for (int it = 0; it < 64; ++it) s += PART[((size_t)b*64 + it)*2048 + j];
  invD[idx] = 1.0f / s;
}

// ---------------- scale G in place: G[b][c][j] *= invD[b][j] ----------------
__global__ __launch_bounds__(256) void k_gscale(__bf16* G, const float* invD){
  int bid = blockIdx.x;                 // 2048 = 8 b * 256 c
  int b = bid >> 8, c = bid & 255;
  int j0 = threadIdx.x * 8;
  __bf16* gp = G + ((size_t)b*256 + c)*2048 + j0;
  bf16x8 g = *(const bf16x8*)gp;
  const float* dp = invD + (size_t)b*2048 + j0;
  f32x4 d0 = *(const f32x4*)dp;
  f32x4 d1 = *(const f32x4*)(dp + 4);
  bf16x8 o;
  #pragma unroll
  for (int e = 0; e < 4; ++e){
    o[e]   = (__bf16)((float)g[e]   * d0[e]);
    o[e+4] = (__bf16)((float)g[e+4] * d1[e]);
  }
  *(bf16x8*)gp = o;
}

// ---------------- pass B: fused QK -> exp -> PV, all operands via LDS ----------------
// grid 256 (b x 32 i-tiles of 64), 512 thr / 8 waves.
// QK: wave = 32i x 16j (iw = w>>2 picks i-half, jw = w&3 picks j-quarter), q[2][8] regs.
// PV: wave = 64i x 32c strip (c0 = w*32), fm=4 x fn=2 x ks=2. 3 barriers/chunk.
__global__ __launch_bounds__(512, 2) void k_attn(const __bf16* Tt, const __bf16* Pt,
                                                 const __bf16* G, __bf16* OT){
  __shared__ __bf16 Ps[64*260];    // phi chunk  (33280 B)
  __shared__ __bf16 Gs[256*68];    // G chunk    (34816 B)
  __shared__ __bf16 Ss[64*68];     // P tile     (8704 B)
  int bid = blockIdx.x;
  int b = bid & 7, it = bid >> 3, i0 = it*64;   // batch -> XCD
  int tid = threadIdx.x, lane = tid & 63, w = tid >> 6;
  int lr = lane & 15, kq = lane >> 4;
  int iw = w >> 2, jw = w & 3;
  const __bf16* Tb = Tt + ((size_t)b*2048 + i0 + iw*32)*256;
  const __bf16* Pb = Pt + (size_t)b*2048*256;
  const __bf16* Gb = G + (size_t)b*256*2048;
  // hoist theta fragments (this wave's 32 i rows)
  bf16x8 q[2][8];
  #pragma unroll
  for (int fm = 0; fm < 2; ++fm)
    #pragma unroll
    for (int ks = 0; ks < 8; ++ks)
      q[fm][ks] = *(const bf16x8*)(Tb + (size_t)(fm*16 + lr)*256 + ks*32 + kq*8);
  f32x4 acc[4][2] = {};
  uint4 sp[4], sg[4];
  // prologue: stage chunk 0 (phi 64x256, G 256x64)
  #pragma unroll
  for (int u = 0; u < 4; ++u){
    int s = u*512 + tid, row = s >> 5, sk = s & 31;
    sp[u] = *(const uint4*)(Pb + (size_t)row*256 + sk*8);
  }
  #pragma unroll
  for (int u = 0; u < 4; ++u){
    int s = u*512 + tid, row = s >> 3, sk = s & 7;
    sg[u] = *(const uint4*)(Gb + (size_t)row*2048 + sk*8);
  }
  #pragma unroll
  for (int u = 0; u < 4; ++u){
    int s = u*512 + tid, row = s >> 5, sk = s & 31;
    *(uint4*)&Ps[row*260 + sk*8] = sp[u];
  }
  #pragma unroll
  for (int u = 0; u < 4; ++u){
    int s = u*512 + tid, row = s >> 3, sk = s & 7;
    *(uint4*)&Gs[row*68 + sk*8] = sg[u];
  }
  __syncthreads();
  for (int ch = 0; ch < 32; ++ch){
    // issue next-chunk global loads early (latency hides under QK+PV)
    if (ch < 31){
      int j0n = (ch + 1)*64;
      #pragma unroll
      for (int u = 0; u < 4; ++u){
        int s = u*512 + tid, row = s >> 5, sk = s & 31;
        sp[u] = *(const uint4*)(Pb + (size_t)(j0n + row)*256 + sk*8);
      }
      #pragma unroll
      for (int u = 0; u < 4; ++u){
        int s = u*512 + tid, row = s >> 3, sk = s & 7;
        sg[u] = *(const uint4*)(Gb + (size_t)row*2048 + j0n + sk*8);
      }
    }
    // QK: this wave's 32i x 16j slice
    f32x4 sa[2] = {};
    #pragma unroll
    for (int ks = 0; ks < 8; ++ks){
      bf16x8 bq = *(const bf16x8*)&Ps[(jw*16 + lr)*260 + ks*32 + kq*8];
      sa[0] = __builtin_amdgcn_mfma_f32_16x16x32_bf16(q[0][ks], bq, sa[0], 0, 0, 0);
      sa[1] = __builtin_amdgcn_mfma_f32_16x16x32_bf16(q[1][ks], bq, sa[1], 0, 0, 0);
    }
    // P = exp(s) -> Ss
    #pragma unroll
    for (int fm = 0; fm < 2; ++fm)
      #pragma unroll
      for (int r = 0; r < 4; ++r)
        Ss[(iw*32 + fm*16 + kq*4 + r)*68 + jw*16 + lr] = (__bf16)exp2f(sa[fm][r] * LOG2E);
    __syncthreads();   // B1: Ss ready (QK done with Ps)
    // PV: out[64i][32c] strip per wave, A = Ss, B = Gs
    #pragma unroll
    for (int ks = 0; ks < 2; ++ks){
      bf16x8 pa[4], gb[2];
      #pragma unroll
      for (int fm = 0; fm < 4; ++fm)
        pa[fm] = *(const bf16x8*)&Ss[(fm*16 + lr)*68 + ks*32 + kq*8];
      #pragma unroll
      for (int fn = 0; fn < 2; ++fn)
        gb[fn] = *(const bf16x8*)&Gs[(w*32 + fn*16 + lr)*68 + ks*32 + kq*8];
      #pragma unroll
      for (int fm = 0; fm < 4; ++fm)
        #pragma unroll
        for (int fn = 0; fn < 2; ++fn)
          acc[fm][fn] = __builtin_amdgcn_mfma_f32_16x16x32_bf16(pa[fm], gb[fn], acc[fm][fn], 0, 0, 0);
    }
    __syncthreads();   // B2: PV done, Ps/Gs/Ss free
    if (ch < 31){
      #pragma unroll
      for (int u = 0; u < 4; ++u){
        int s = u*512 + tid, row = s >> 5, sk = s & 31;
        *(uint4*)&Ps[row*260 + sk*8] = sp[u];
      }
      #pragma unroll
      for (int u = 0; u < 4; ++u){
        int s = u*512 + tid, row = s >> 3, sk = s & 7;
        *(uint4*)&Gs[row*68 + sk*8] = sg[u];
      }
    }
    __syncthreads();   // B3: next chunk staged
  }
  // epilogue: out[i][c'] -> OT[p][ic], ic=c'>>1, p=(c'&1)*2048+i
  #pragma unroll
  for (int fm = 0; fm < 4; ++fm)
    #pragma unroll
    for (int fn = 0; fn < 2; ++fn)
      #pragma unroll
      for (int r = 0; r < 4; ++r){
        int i = i0 + fm*16 + kq*4 + r;
        int cp = w*32 + fn*16 + lr;
        int p = ((cp & 1) << 11) + i;
        OT[((size_t)b*4096 + p)*128 + (cp >> 1)] = (__bf16)acc[fm][fn][r];
      }
}

// ---------------- mask conv + residual: OT(4096x128) * Wm^T(256x128) + x ----------------
__global__ __launch_bounds__(256) void k_mask(const __bf16* OT, const __bf16* Wm,
                                              const float* x, float* out){
  __shared__ __bf16 As[128*72];
  __shared__ __bf16 Bs[64*72];
  int b = blockIdx.z, p0 = blockIdx.x*128, o0 = blockIdx.y*64;
  int tid = threadIdx.x, lane = tid & 63, wave = tid >> 6;
  int wm = wave >> 1, wn = wave & 1;
  f32x4 acc[4][2] = {};
  const __bf16* Ab = OT + ((size_t)b*4096 + p0)*128;
  const __bf16* Bb = Wm + (size_t)o0*128;
  for (int kc = 0; kc < 2; ++kc){
    int k0 = kc*64;
    #pragma unroll
    for (int itc = 0; itc < 4; ++itc){
      int s = tid + itc*256, row = s >> 3, sk = s & 7;
      *(uint4*)&As[row*72 + sk*8] = *(const uint4*)(Ab + (size_t)row*128 + k0 + sk*8);
    }
    #pragma unroll
    for (int itc = 0; itc < 2; ++itc){
      int s = tid + itc*256, row = s >> 3, sk = s & 7;
      *(uint4*)&Bs[row*72 + sk*8] = *(const uint4*)(Bb + (size_t)row*128 + k0 + sk*8);
    }
    __syncthreads();
    #pragma unroll
    for (int ks = 0; ks < 2; ++ks){
      int koff = ks*32 + (lane>>4)*8;
      bf16x8 af[4], bfr[2];
      #pragma unroll
      for (int fm = 0; fm < 4; ++fm)
        af[fm] = *(const bf16x8*)&As[(wm*64 + fm*16 + (lane&15))*72 + koff];
      #pragma unroll
      for (int fn = 0; fn < 2; ++fn)
        bfr[fn] = *(const bf16x8*)&Bs[(wn*32 + fn*16 + (lane&15))*72 + koff];
      #pragma unroll
      for (int fm = 0; fm < 4; ++fm)
        #pragma unroll
        for (int fn = 0; fn < 2; ++fn)
          acc[fm][fn] = __builtin_amdgcn_mfma_f32_16x16x32_bf16(af[fm], bfr[fn], acc[fm][fn], 0, 0, 0);
    }
    __syncthreads();
  }
  #pragma unroll
  for (int fm = 0; fm < 4; ++fm)
    #pragma unroll
    for (int fn = 0; fn < 2; ++fn){
      int pb = p0 + wm*64 + fm*16 + (lane>>4)*4;
      int o = o0 + wn*32 + fn*16 + (lane&15);
      size_t idx = ((size_t)b*256 + o)*4096 + pb;
      f32x4 xv = *(const f32x4*)(x + idx);
      f32x4 ov = acc[fm][fn] + xv;
      *(f32x4*)(out + idx) = ov;
    }
}

extern "C" void kernel_launch(void* const* d_in, const int* in_sizes, int n_in,
                              void* d_out, int out_size, void* d_ws, size_t ws_size,
                              hipStream_t stream){
  if (ws_size < WS_NEED) return;  // workspace too small; fail visibly
  const float* x  = (const float*)d_in[0];
  const float* wt = (const float*)d_in[1];
  const float* wp = (const float*)d_in[2];
  const float* wg = (const float*)d_in[3];
  const float* wm = (const float*)d_in[4];
  char* ws = (char*)d_ws;
  __bf16* Xt  = (__bf16*)(ws + XT_OFF);
  __bf16* Tt  = (__bf16*)(ws + TT_OFF);
  __bf16* Pt  = (__bf16*)(ws + PT_OFF);
  __bf16* G   = (__bf16*)(ws + G_OFF);
  __bf16* OT  = (__bf16*)(ws + OT_OFF);
  __bf16* W3  = (__bf16*)(ws + W3_OFF);
  __bf16* Wm  = (__bf16*)(ws + WM_OFF);
  float* PART = (float*)(ws + PART_OFF);   // aliases Xt (dead after k_conv3)
  float* invD = (float*)(ws + ID_OFF);
  float* out  = (float*)d_out;

  k_weights<<<512, 256, 0, stream>>>(wt, wp, wg, wm, W3, Wm);
  k_xt<<<dim3(64, 4, 8), 256, 0, stream>>>(x, Xt);
  k_conv3<<<dim3(32, 6, 8), 256, 0, stream>>>(Xt, W3, Tt, Pt, G);
  k_colsum<<<512, 512, 0, stream>>>(Tt, Pt, PART);
  k_invd<<<64, 256, 0, stream>>>(PART, invD);
  k_gscale<<<2048, 256, 0, stream>>>(G, invD);
  k_attn<<<256, 512, 0, stream>>>(Tt, Pt, G, OT);
  k_mask<<<dim3(32, 4, 8), 256, 0, stream>>>(OT, Wm, x, out);
}

// Round 5
// 156.085 us; speedup vs baseline: 3.1424x; 2.6449x over previous
//
#include <hip/hip_runtime.h>

typedef __attribute__((ext_vector_type(8))) __bf16 bf16x8;
typedef __attribute__((ext_vector_type(4))) float f32x4;

#define LOG2E 1.4426950408889634f

// ---- workspace byte offsets ----
// OTacc aliases Xt (Xt dead after k_conv3). S slices live in d_out.
#define XT_OFF   0ul          // Xt   : bf16 [8][4096][256] / OTacc: f32 [8][4096][128]
#define OTA_OFF  0ul
#define TT_OFF   16777216ul   // Tt  : bf16 [8][2048][256]  (x_theta, n-major)
#define PT_OFF   25165824ul   // Pt  : bf16 [8][2048][256]  (x_phi, n-major)
#define G_OFF    33554432ul   // G   : bf16 [8][256][2048]  (x_g, c-major; scaled per-slice)
#define W3_OFF   41943040ul   // W3  : bf16 [384][256]
#define WM_OFF   42139648ul   // Wm  : bf16 [256][128]
#define ID_OFF   42205184ul   // invD: f32  [8][2048]
#define PART_OFF 42270720ul   // PART: f32  [8][32][1024] per-slice column partials
#define WS_NEED  43319296ul

// async global->LDS, 16B per lane, wave-uniform LDS base
__device__ __forceinline__ void gload16(const __bf16* g, __bf16* l){
  __builtin_amdgcn_global_load_lds((const __attribute__((address_space(1))) void*)g,
                                   (__attribute__((address_space(3))) void*)l, 16, 0, 0);
}

// ---------------- weights cast ----------------
__global__ __launch_bounds__(256) void k_weights(const float* wt, const float* wp,
                                                 const float* wg, const float* wm,
                                                 __bf16* W3, __bf16* Wm){
  int idx = blockIdx.x*256 + threadIdx.x;
  if (idx < 98304){
    float v = (idx < 32768) ? wt[idx] : (idx < 65536) ? wp[idx - 32768] : wg[idx - 65536];
    W3[idx] = (__bf16)v;
  } else if (idx < 131072){
    Wm[idx - 98304] = (__bf16)wm[idx - 98304];
  }
}

// ---------------- transpose+cast x: (b,256,4096) f32 -> Xt (b,4096,256) bf16 ----------------
__global__ __launch_bounds__(256) void k_xt(const float* x, __bf16* Xt){
  __shared__ float tile[64][65];
  int b = blockIdx.z, c0 = blockIdx.y*64, p0 = blockIdx.x*64;
  int t = threadIdx.x, col = t & 63, r0 = t >> 6;
  const float* xb = x + ((size_t)b*256 + c0)*4096 + p0;
  #pragma unroll
  for (int rr = 0; rr < 16; ++rr){
    int row = rr*4 + r0;
    tile[row][col] = xb[(size_t)row*4096 + col];
  }
  __syncthreads();
  __bf16* xo = Xt + ((size_t)b*4096 + p0)*256 + c0;
  #pragma unroll
  for (int rr = 0; rr < 16; ++rr){
    int prow = rr*4 + r0;
    xo[(size_t)prow*256 + col] = (__bf16)tile[col][prow];
  }
}

// ---------------- conv3: Xt(4096x256) * W3^T(384x256) -> theta/phi/g in attn layouts ----------------
__global__ __launch_bounds__(256) void k_conv3(const __bf16* Xt, const __bf16* W3,
                                               __bf16* Tt, __bf16* Pt, __bf16* G){
  __shared__ __bf16 As[128*72];
  __shared__ __bf16 Bs[64*72];
  int b = blockIdx.z, p0 = blockIdx.x*128, o0 = blockIdx.y*64;
  int tid = threadIdx.x, lane = tid & 63, wave = tid >> 6;
  int wm = wave >> 1, wn = wave & 1;
  f32x4 acc[4][2] = {};
  const __bf16* Ab = Xt + ((size_t)b*4096 + p0)*256;
  const __bf16* Bb = W3 + (size_t)o0*256;
  for (int kc = 0; kc < 4; ++kc){
    int k0 = kc*64;
    #pragma unroll
    for (int it = 0; it < 4; ++it){
      int s = tid + it*256, row = s >> 3, sk = s & 7;
      *(uint4*)&As[row*72 + sk*8] = *(const uint4*)(Ab + (size_t)row*256 + k0 + sk*8);
    }
    #pragma unroll
    for (int it = 0; it < 2; ++it){
      int s = tid + it*256, row = s >> 3, sk = s & 7;
      *(uint4*)&Bs[row*72 + sk*8] = *(const uint4*)(Bb + (size_t)row*256 + k0 + sk*8);
    }
    __syncthreads();
    #pragma unroll
    for (int ks = 0; ks < 2; ++ks){
      int koff = ks*32 + (lane>>4)*8;
      bf16x8 af[4], bfr[2];
      #pragma unroll
      for (int fm = 0; fm < 4; ++fm)
        af[fm] = *(const bf16x8*)&As[(wm*64 + fm*16 + (lane&15))*72 + koff];
      #pragma unroll
      for (int fn = 0; fn < 2; ++fn)
        bfr[fn] = *(const bf16x8*)&Bs[(wn*32 + fn*16 + (lane&15))*72 + koff];
      #pragma unroll
      for (int fm = 0; fm < 4; ++fm)
        #pragma unroll
        for (int fn = 0; fn < 2; ++fn)
          acc[fm][fn] = __builtin_amdgcn_mfma_f32_16x16x32_bf16(af[fm], bfr[fn], acc[fm][fn], 0, 0, 0);
    }
    __syncthreads();
  }
  // scatter per the reshape-view: flat = o*4096+p -> c = 2o+(p>>11), n = p&2047
  #pragma unroll
  for (int fm = 0; fm < 4; ++fm)
    #pragma unroll
    for (int fn = 0; fn < 2; ++fn)
      #pragma unroll
      for (int r = 0; r < 4; ++r){
        int p = p0 + wm*64 + fm*16 + (lane>>4)*4 + r;
        int o = o0 + wn*32 + fn*16 + (lane&15);
        __bf16 v = (__bf16)acc[fm][fn][r];
        int i = p & 2047, ph = p >> 11;
        if (o < 128)      Tt[((size_t)b*2048 + i)*256 + 2*o + ph] = v;
        else if (o < 256) Pt[((size_t)b*2048 + i)*256 + 2*(o-128) + ph] = v;
        else              G [((size_t)b*256 + 2*(o-256) + ph)*2048 + i] = v;
      }
}

// ---------------- GEMM1: S = exp(Tt . Pt^T) for j-slice, + column partial sums ----------------
// 128x128 tile, BK=64, 4 waves (2x2), global_load_lds + XOR-swizzled LDS, 2 barriers/K-step.
__global__ __launch_bounds__(256) void k_sexp(const __bf16* Tt, const __bf16* Pt,
                                              __bf16* S, float* PART, int js0){
  __shared__ __bf16 As[128*64];
  __shared__ __bf16 Bs[128*64];
  int bid = blockIdx.x;
  int b = bid & 7, r2 = bid >> 3;
  int m = r2 & 15, n = r2 >> 4;          // m: 16 i-tiles, n: 8 j-tiles (slice)
  int m0 = m*128;
  int tid = threadIdx.x, lane = tid & 63, w = tid >> 6;
  int lr = lane & 15, kq = lane >> 4;
  int wm = w >> 1, wn = w & 1;
  const __bf16* Ab = Tt + ((size_t)b*2048 + m0)*256;
  const __bf16* Bb = Pt + ((size_t)b*2048 + js0 + n*128)*256;
  // per-lane staging source (inverse-swizzled column so LDS-linear dest + swizzled read agree)
  int laneRow = lane >> 3;
  int laneSw  = ((lane & 7) ^ laneRow) * 8;
  const __bf16* ga = Ab + (size_t)laneRow*256 + laneSw;
  const __bf16* gb = Bb + (size_t)laneRow*256 + laneSw;
  f32x4 acc[4][4] = {};
  for (int kc = 0; kc < 4; ++kc){
    int k0 = kc*64;
    #pragma unroll
    for (int u = 0; u < 4; ++u){
      int c = w*4 + u;
      gload16(ga + (size_t)c*8*256 + k0, &As[c*512]);
      gload16(gb + (size_t)c*8*256 + k0, &Bs[c*512]);
    }
    __syncthreads();
    #pragma unroll
    for (int ks = 0; ks < 2; ++ks){
      bf16x8 af[4], bf[4];
      #pragma unroll
      for (int fm = 0; fm < 4; ++fm){
        int ar = wm*64 + fm*16 + lr;
        af[fm] = *(const bf16x8*)&As[ar*64 + (((ks*4 + kq) ^ (ar & 7))*8)];
      }
      #pragma unroll
      for (int fn = 0; fn < 4; ++fn){
        int br = wn*64 + fn*16 + lr;
        bf[fn] = *(const bf16x8*)&Bs[br*64 + (((ks*4 + kq) ^ (br & 7))*8)];
      }
      #pragma unroll
      for (int fm = 0; fm < 4; ++fm)
        #pragma unroll
        for (int fn = 0; fn < 4; ++fn)
          acc[fm][fn] = __builtin_amdgcn_mfma_f32_16x16x32_bf16(af[fm], bf[fn], acc[fm][fn], 0, 0, 0);
    }
    __syncthreads();
  }
  // epilogue: e = exp(s); store bf16 e; column sums -> PART
  __bf16* Sb = S + ((size_t)b*2048 + m0)*1024 + n*128;
  #pragma unroll
  for (int fn = 0; fn < 4; ++fn){
    int jc = wn*64 + fn*16 + lr;           // col within 128-tile
    float v = 0.f;
    #pragma unroll
    for (int fm = 0; fm < 4; ++fm){
      int ib = wm*64 + fm*16 + kq*4;
      #pragma unroll
      for (int r = 0; r < 4; ++r){
        float e = exp2f(acc[fm][fn][r] * LOG2E);
        v += e;
        Sb[(size_t)(ib + r)*1024 + jc] = (__bf16)e;
      }
    }
    v += __shfl_xor(v, 16);
    v += __shfl_xor(v, 32);
    if (kq == 0)
      PART[((size_t)b*32 + m*2 + wm)*1024 + n*128 + jc] = v;
  }
}

// ---------------- reduce partials -> invD = 1/D for slice ----------------
__global__ __launch_bounds__(256) void k_invd(const float* PART, float* invD, int js0){
  int bid = blockIdx.x;                  // 32
  int b = bid & 7, seg = bid >> 3;
  int jl = seg*256 + threadIdx.x;        // 0..1023
  float s = 0.f;
  #pragma unroll
  for (int it = 0; it < 32; ++it) s += PART[((size_t)b*32 + it)*1024 + jl];
  invD[(size_t)b*2048 + js0 + jl] = 1.0f / s;
}

// ---------------- scale G slice columns in place ----------------
__global__ __launch_bounds__(256) void k_gscale(__bf16* G, const float* invD, int js0){
  int bid = blockIdx.x;                  // 2048 = 8 b * 256 c
  int b = bid >> 8, c = bid & 255;
  int jl = threadIdx.x * 4;
  __bf16* gp = G + ((size_t)b*256 + c)*2048 + js0 + jl;
  const float* dp = invD + (size_t)b*2048 + js0 + jl;
  f32x4 d = *(const f32x4*)dp;
  __bf16 gv[4];
  *(uint2*)gv = *(const uint2*)gp;
  #pragma unroll
  for (int e = 0; e < 4; ++e) gv[e] = (__bf16)((float)gv[e] * d[e]);
  *(uint2*)gp = *(const uint2*)gv;
}

// ---------------- GEMM2: OTacc (+)= S_slice . G'^T ----------------
// M=2048(i), N=256(c), K=1024(slice j). 128x64 tile, BK=64, 4 waves (2x2).
__global__ __launch_bounds__(256) void k_pv(const __bf16* S, const __bf16* G,
                                            float* OTacc, int js0, int first){
  __shared__ __bf16 As[128*64];
  __shared__ __bf16 Bs[64*64];
  int bid = blockIdx.x;
  int b = bid & 7, r2 = bid >> 3;
  int m = r2 & 15, n = r2 >> 4;          // m: 16 i-tiles, n: 4 c-tiles
  int m0 = m*128, n0 = n*64;
  int tid = threadIdx.x, lane = tid & 63, w = tid >> 6;
  int lr = lane & 15, kq = lane >> 4;
  int wm = w >> 1, wn = w & 1;
  const __bf16* Ab = S + ((size_t)b*2048 + m0)*1024;            // lda 1024
  const __bf16* Bb = G + ((size_t)b*256 + n0)*2048 + js0;       // ldb 2048
  int laneRow = lane >> 3;
  int laneSw  = ((lane & 7) ^ laneRow) * 8;
  const __bf16* ga = Ab + (size_t)laneRow*1024 + laneSw;
  const __bf16* gb = Bb + (size_t)laneRow*2048 + laneSw;
  f32x4 acc[4][2] = {};
  for (int kc = 0; kc < 16; ++kc){
    int k0 = kc*64;
    #pragma unroll
    for (int u = 0; u < 4; ++u){
      int c = w*4 + u;
      gload16(ga + (size_t)c*8*1024 + k0, &As[c*512]);
    }
    #pragma unroll
    for (int u = 0; u < 2; ++u){
      int c = w*2 + u;
      gload16(gb + (size_t)c*8*2048 + k0, &Bs[c*512]);
    }
    __syncthreads();
    #pragma unroll
    for (int ks = 0; ks < 2; ++ks){
      bf16x8 af[4], bf[2];
      #pragma unroll
      for (int fm = 0; fm < 4; ++fm){
        int ar = wm*64 + fm*16 + lr;
        af[fm] = *(const bf16x8*)&As[ar*64 + (((ks*4 + kq) ^ (ar & 7))*8)];
      }
      #pragma unroll
      for (int fn = 0; fn < 2; ++fn){
        int br = wn*32 + fn*16 + lr;
        bf[fn] = *(const bf16x8*)&Bs[br*64 + (((ks*4 + kq) ^ (br & 7))*8)];
      }
      #pragma unroll
      for (int fm = 0; fm < 4; ++fm)
        #pragma unroll
        for (int fn = 0; fn < 2; ++fn)
          acc[fm][fn] = __builtin_amdgcn_mfma_f32_16x16x32_bf16(af[fm], bf[fn], acc[fm][fn], 0, 0, 0);
    }
    __syncthreads();
  }
  // epilogue: scatter into OTacc[b][p][ic], p=(c&1)*2048+i, ic=c>>1 (L2-resident)
  float* Ob = OTacc + (size_t)b*4096*128;
  if (first){
    #pragma unroll
    for (int fm = 0; fm < 4; ++fm)
      #pragma unroll
      for (int fn = 0; fn < 2; ++fn)
        #pragma unroll
        for (int r = 0; r < 4; ++r){
          int i = m0 + wm*64 + fm*16 + kq*4 + r;
          int c = n0 + wn*32 + fn*16 + lr;
          Ob[(size_t)(((c & 1) << 11) + i)*128 + (c >> 1)] = acc[fm][fn][r];
        }
  } else {
    #pragma unroll
    for (int fm = 0; fm < 4; ++fm)
      #pragma unroll
      for (int fn = 0; fn < 2; ++fn)
        #pragma unroll
        for (int r = 0; r < 4; ++r){
          int i = m0 + wm*64 + fm*16 + kq*4 + r;
          int c = n0 + wn*32 + fn*16 + lr;
          size_t idx = (size_t)(((c & 1) << 11) + i)*128 + (c >> 1);
          Ob[idx] += acc[fm][fn][r];
        }
  }
}

// ---------------- mask conv + residual: OTacc(4096x128 f32) * Wm^T(256x128) + x ----------------
__global__ __launch_bounds__(256) void k_mask(const float* OTacc, const __bf16* Wm,
                                              const float* x, float* out){
  __shared__ __bf16 As[128*72];
  __shared__ __bf16 Bs[64*72];
  int b = blockIdx.z, p0 = blockIdx.x*128, o0 = blockIdx.y*64;
  int tid = threadIdx.x, lane = tid & 63, wave = tid >> 6;
  int wm = wave >> 1, wn = wave & 1;
  f32x4 acc[4][2] = {};
  const float* Ab = OTacc + ((size_t)b*4096 + p0)*128;
  const __bf16* Bb = Wm + (size_t)o0*128;
  for (int kc = 0; kc < 2; ++kc){
    int k0 = kc*64;
    #pragma unroll
    for (int it = 0; it < 8; ++it){
      int idx = it*256 + tid;            // 2048 f32x4 groups = 128 rows x 64 k
      int row = idx >> 4, c4 = (idx & 15)*4;
      f32x4 vv = *(const f32x4*)(Ab + (size_t)row*128 + k0 + c4);
      __bf16 tmp[4];
      #pragma unroll
      for (int e = 0; e < 4; ++e) tmp[e] = (__bf16)vv[e];
      *(uint2*)&As[row*72 + c4] = *(const uint2*)tmp;
    }
    #pragma unroll
    for (int itc = 0; itc < 2; ++itc){
      int s = tid + itc*256, row = s >> 3, sk = s & 7;
      *(uint4*)&Bs[row*72 + sk*8] = *(const uint4*)(Bb + (size_t)row*128 + k0 + sk*8);
    }
    __syncthreads();
    #pragma unroll
    for (int ks = 0; ks < 2; ++ks){
      int koff = ks*32 + (lane>>4)*8;
      bf16x8 af[4], bfr[2];
      #pragma unroll
      for (int fm = 0; fm < 4; ++fm)
        af[fm] = *(const bf16x8*)&As[(wm*64 + fm*16 + (lane&15))*72 + koff];
      #pragma unroll
      for (int fn = 0; fn < 2; ++fn)
        bfr[fn] = *(const bf16x8*)&Bs[(wn*32 + fn*16 + (lane&15))*72 + koff];
      #pragma unroll
      for (int fm = 0; fm < 4; ++fm)
        #pragma unroll
        for (int fn = 0; fn < 2; ++fn)
          acc[fm][fn] = __builtin_amdgcn_mfma_f32_16x16x32_bf16(af[fm], bfr[fn], acc[fm][fn], 0, 0, 0);
    }
    __syncthreads();
  }
  #pragma unroll
  for (int fm = 0; fm < 4; ++fm)
    #pragma unroll
    for (int fn = 0; fn < 2; ++fn){
      int pb = p0 + wm*64 + fm*16 + (lane>>4)*4;
      int o = o0 + wn*32 + fn*16 + (lane&15);
      size_t idx = ((size_t)b*256 + o)*4096 + pb;
      f32x4 xv = *(const f32x4*)(x + idx);
      f32x4 ov = acc[fm][fn] + xv;
      *(f32x4*)(out + idx) = ov;
    }
}

extern "C" void kernel_launch(void* const* d_in, const int* in_sizes, int n_in,
                              void* d_out, int out_size, void* d_ws, size_t ws_size,
                              hipStream_t stream){
  if (ws_size < WS_NEED) return;  // workspace too small; fail visibly
  const float* x  = (const float*)d_in[0];
  const float* wt = (const float*)d_in[1];
  const float* wp = (const float*)d_in[2];
  const float* wg = (const float*)d_in[3];
  const float* wm = (const float*)d_in[4];
  char* ws = (char*)d_ws;
  __bf16* Xt   = (__bf16*)(ws + XT_OFF);
  float* OTacc = (float*)(ws + OTA_OFF);   // aliases Xt (dead after conv3)
  __bf16* Tt   = (__bf16*)(ws + TT_OFF);
  __bf16* Pt   = (__bf16*)(ws + PT_OFF);
  __bf16* G    = (__bf16*)(ws + G_OFF);
  __bf16* W3   = (__bf16*)(ws + W3_OFF);
  __bf16* Wm   = (__bf16*)(ws + WM_OFF);
  float* invD  = (float*)(ws + ID_OFF);
  float* PART  = (float*)(ws + PART_OFF);
  __bf16* S    = (__bf16*)d_out;           // S slice scratch lives in d_out
  float* out   = (float*)d_out;

  k_weights<<<512, 256, 0, stream>>>(wt, wp, wg, wm, W3, Wm);
  k_xt<<<dim3(64, 4, 8), 256, 0, stream>>>(x, Xt);
  k_conv3<<<dim3(32, 6, 8), 256, 0, stream>>>(Xt, W3, Tt, Pt, G);
  for (int s = 0; s < 2; ++s){
    int js0 = s * 1024;
    k_sexp<<<1024, 256, 0, stream>>>(Tt, Pt, S, PART, js0);
    k_invd<<<32, 256, 0, stream>>>(PART, invD, js0);
    k_gscale<<<2048, 256, 0, stream>>>(G, invD, js0);
    k_pv<<<512, 256, 0, stream>>>(S, G, OTacc, js0, s == 0 ? 1 : 0);
  }
  k_mask<<<dim3(32, 4, 8), 256, 0, stream>>>(OTacc, Wm, x, out);
}